// Round 4
// baseline (3344.947 us; speedup 1.0000x reference)
//
#include <hip/hip_runtime.h>
#include <math.h>

#define L 10
#define B 4
#define H 256
#define W 256
#define HID 100
#define SIGMA 4.0f
#define KSIZE 25
#define KHALF 12
#define MU 0.02f
#define SLOPE 0.01f
#define HW (H*W)

// ---------------------------------------------------------------- helpers

__device__ __forceinline__ float tap2(const float* __restrict__ im, int y, int x) {
    return (x >= 0 && x < W && y >= 0 && y < H) ? im[y * W + x] : 0.f;
}

__device__ __forceinline__ float bilin(const float* __restrict__ im, float x, float y) {
    float xf = floorf(x), yf = floorf(y);
    int x0 = (int)xf, y0 = (int)yf;
    float wx = x - xf, wy = y - yf;
    float v00 = tap2(im, y0, x0),     v01 = tap2(im, y0, x0 + 1);
    float v10 = tap2(im, y0 + 1, x0), v11 = tap2(im, y0 + 1, x0 + 1);
    return v00 * (1.f - wx) * (1.f - wy) + v01 * wx * (1.f - wy)
         + v10 * (1.f - wx) * wy         + v11 * wx * wy;
}

__device__ __forceinline__ void gaussw(float g[KSIZE]) {
    float s = 0.f;
#pragma unroll
    for (int k = 0; k < KSIZE; ++k) {
        float r = ((float)k - (float)KHALF) * (1.f / SIGMA);
        float v = expf(-0.5f * r * r);
        g[k] = v; s += v;
    }
    float inv = 1.f / s;
#pragma unroll
    for (int k = 0; k < KSIZE; ++k) g[k] *= inv;
}

// ---------------------------------------------------------------- init

__global__ void init_kernel(const float* __restrict__ source, const float* __restrict__ z0,
                            float* __restrict__ res0_out, float* __restrict__ rd0,
                            float* __restrict__ phi0, float* __restrict__ image_buf) {
    int idx = blockIdx.x * 256 + threadIdx.x;
    if (idx >= B * HW) return;
    int b = idx / HW, p = idx % HW;
    int y = p / W, x = p % W;
    float z = z0[p];
    res0_out[idx] = z;
    rd0[(size_t)(b * 11 + 0) * HW + p] = z;
    image_buf[idx] = source[idx];
    phi0[(size_t)(b * 2 + 0) * HW + p] = (float)x;
    phi0[(size_t)(b * 2 + 1) * HW + p] = (float)y;
}

// ------------------------------------- fused sobel + t + vblur + hblur

__global__ __launch_bounds__(256)
void field_kernel(const float* __restrict__ img, const float* __restrict__ res,
                  float* __restrict__ grads_l, float* __restrict__ field_l) {
    __shared__ float s_img[58][59];
    __shared__ float s_t[2][56][57];
    __shared__ float s_vb[2][32][57];

    const int tid = threadIdx.x;
    const int b = blockIdx.z;
    const int TY0 = blockIdx.y * 32, TX0 = blockIdx.x * 32;
    const float* imb = img + (size_t)b * HW;
    const float* reb = res + (size_t)b * HW;

    for (int q = tid; q < 58 * 58; q += 256) {
        int sy = q / 58, sx = q % 58;
        int gy = min(max(TY0 - 13 + sy, 0), H - 1);
        int gx = min(max(TX0 - 13 + sx, 0), W - 1);
        s_img[sy][sx] = imb[gy * W + gx];
    }
    __syncthreads();

    for (int q = tid; q < 56 * 56; q += 256) {
        int py = q / 56, px = q % 56;
        int sy = py + 1, sx = px + 1;
        float a00 = s_img[sy-1][sx-1], a01 = s_img[sy-1][sx], a02 = s_img[sy-1][sx+1];
        float a10 = s_img[sy  ][sx-1],                         a12 = s_img[sy  ][sx+1];
        float a20 = s_img[sy+1][sx-1], a21 = s_img[sy+1][sx], a22 = s_img[sy+1][sx+1];
        float dx = (a02 - a00 + 2.f * (a12 - a10) + a22 - a20) * 0.125f;
        float dy = (a20 - a00 + 2.f * (a21 - a01) + a22 - a02) * 0.125f;
        int gy = TY0 - 12 + py, gx = TX0 - 12 + px;
        bool in = ((unsigned)gy < H) && ((unsigned)gx < W);
        float rv = in ? reb[gy * W + gx] : 0.f;
        s_t[0][py][px] = in ? -rv * dx : 0.f;
        s_t[1][py][px] = in ? -rv * dy : 0.f;
        if (py >= 12 && py < 44 && px >= 12 && px < 44) {
            grads_l[(size_t)(b * 2 + 0) * HW + gy * W + gx] = dx;
            grads_l[(size_t)(b * 2 + 1) * HW + gy * W + gx] = dy;
        }
    }
    __syncthreads();

    float g[KSIZE]; gaussw(g);

    for (int q = tid; q < 2 * 32 * 56; q += 256) {
        int ch = q / (32 * 56), r = q % (32 * 56);
        int vy = r / 56, vx = r % 56;
        float acc = 0.f;
#pragma unroll
        for (int k = 0; k < KSIZE; ++k) acc = fmaf(g[k], s_t[ch][vy + k][vx], acc);
        s_vb[ch][vy][vx] = acc;
    }
    __syncthreads();

    for (int q = tid; q < 2 * 32 * 32; q += 256) {
        int ch = q / 1024, p = q % 1024;
        int hy = p / 32, hx = p % 32;
        float acc = 0.f;
#pragma unroll
        for (int k = 0; k < KSIZE; ++k) acc = fmaf(g[k], s_vb[ch][hy][hx + k], acc);
        field_l[((size_t)(b * H + TY0 + hy) * W + TX0 + hx) * 2 + ch] = acc;
    }
}

// ------------------------------------------------- fused res_block v3
// 16x16 tile, 100 channels split into 2 groups across blockIdx.z
// -> grid 16*16*8 = 2048 blocks = 8 blocks/CU (vs 2 before).
// Each group writes its partial conv2 sum; efg combines (no atomics).

#define NCH 10

__global__ __launch_bounds__(256)
void resblock_kernel(const float* __restrict__ res_i, const float* __restrict__ img,
                     const float* __restrict__ w1, const float* __restrict__ b1,
                     const float* __restrict__ w2, float* __restrict__ part) {
    __shared__ float s_in[2][20][21];      // tile + halo2, zero-padded
    __shared__ float s_hid[NCH][18][20];   // hidden 18x18, stride 20 (even)

    const int tid = threadIdx.x;
    const int z = blockIdx.z;
    const int b = z & 3;
    const int g = z >> 2;                  // channel group 0/1 (50 ch each)
    const int TY0 = blockIdx.y * 16, TX0 = blockIdx.x * 16;

    for (int q = tid; q < 20 * 20; q += 256) {
        int ry = q / 20, rx = q % 20;
        int gy = TY0 - 2 + ry, gx = TX0 - 2 + rx;
        bool v = ((unsigned)gy < H) && ((unsigned)gx < W);
        size_t gp = (size_t)b * HW + gy * W + gx;
        s_in[0][ry][rx] = v ? res_i[gp] : 0.f;
        s_in[1][ry][rx] = v ? img[gp]   : 0.f;
    }
    __syncthreads();

    const int ty = tid >> 4, tx = tid & 15;
    float acc = 0.f;

    for (int cc = 0; cc < 5; ++cc) {
        // conv1: hidden 18x18 as 18 rows x 9 col-pairs = 162 units
        if (tid < 162) {
            int hy = tid / 9, hx2 = (tid % 9) * 2;
            int gy = TY0 - 1 + hy, gx0 = TX0 - 1 + hx2;
            float xv[2][3][4];
#pragma unroll
            for (int ic = 0; ic < 2; ++ic)
#pragma unroll
                for (int j = 0; j < 3; ++j)
#pragma unroll
                    for (int i = 0; i < 4; ++i)
                        xv[ic][j][i] = s_in[ic][hy + j][hx2 + i];
            bool gyok = ((unsigned)gy < H);
            bool in0 = gyok && ((unsigned)gx0 < W);
            bool in1 = gyok && ((unsigned)(gx0 + 1) < W);
#pragma unroll 2
            for (int c = 0; c < NCH; ++c) {
                int ch = g * 50 + cc * NCH + c;
                const float* wp = w1 + ch * 18;       // uniform -> s_load
                float bv = b1[ch];
                float h0 = bv, h1 = bv;
#pragma unroll
                for (int ic = 0; ic < 2; ++ic)
#pragma unroll
                    for (int j = 0; j < 3; ++j)
#pragma unroll
                        for (int i = 0; i < 3; ++i) {
                            float wv = wp[ic * 9 + j * 3 + i];
                            h0 = fmaf(wv, xv[ic][j][i],     h0);
                            h1 = fmaf(wv, xv[ic][j][i + 1], h1);
                        }
                h0 = (h0 >= 0.f) ? h0 : SLOPE * h0;
                h1 = (h1 >= 0.f) ? h1 : SLOPE * h1;
                // conv2 zero-pads the hidden map outside the image
                s_hid[c][hy][hx2]     = in0 ? h0 : 0.f;
                s_hid[c][hy][hx2 + 1] = in1 ? h1 : 0.f;
            }
        }
        __syncthreads();

        for (int c = 0; c < NCH; ++c) {
            const float* wq = w2 + (g * 50 + cc * NCH + c) * 9;  // uniform
#pragma unroll
            for (int j = 0; j < 3; ++j) {
                float v0 = s_hid[c][ty + j][tx + 0];
                float v1 = s_hid[c][ty + j][tx + 1];
                float v2 = s_hid[c][ty + j][tx + 2];
                acc = fmaf(wq[j * 3 + 0], v0, acc);
                acc = fmaf(wq[j * 3 + 1], v1, acc);
                acc = fmaf(wq[j * 3 + 2], v2, acc);
            }
        }
        __syncthreads();
    }

    size_t gp = (size_t)b * HW + (TY0 + ty) * W + TX0 + tx;
    part[(size_t)g * (B * HW) + gp] = acc;
}

// ------------------------------------------------- E+F+G fused warp/update
// also combines the two resblock partials into res_{i+1}

__global__ void efg_kernel(const float* __restrict__ field,
                           const float* __restrict__ res_prev,   // residuals[i]
                           const float* __restrict__ part,       // 2 x B*HW partials
                           float* __restrict__ res_next,         // residuals[i+1] out
                           const float* __restrict__ rd_old, float* __restrict__ rd_new,
                           int nc_old,
                           const float* __restrict__ phi_old, float* __restrict__ phi_new,
                           const float* __restrict__ seg, const float* __restrict__ source,
                           float* __restrict__ image_buf, float* __restrict__ image_out) {
    int idx = blockIdx.x * 256 + threadIdx.x;
    if (idx >= B * HW) return;
    int b = idx / HW, p = idx % HW;
    int y = p / W, x = p % W;

    float rn = res_prev[idx] + (part[idx] + part[(size_t)B * HW + idx]) * (1.f / (float)L);
    res_next[idx] = rn;

    float fx = field[((size_t)(b * HW + p)) * 2 + 0];
    float fy = field[((size_t)(b * HW + p)) * 2 + 1];
    float sx = (float)x - fx * (1.f / (float)L);
    float sy = (float)y - fy * (1.f / (float)L);

    float xf = floorf(sx), yf = floorf(sy);
    int x0 = (int)xf, y0 = (int)yf;
    float wx = sx - xf, wy = sy - yf;
    float mx0 = (x0 >= 0 && x0 < W) ? 1.f : 0.f;
    float mx1 = (x0 + 1 >= 0 && x0 + 1 < W) ? 1.f : 0.f;
    float my0 = (y0 >= 0 && y0 < H) ? 1.f : 0.f;
    float my1 = (y0 + 1 >= 0 && y0 + 1 < H) ? 1.f : 0.f;
    float W00 = (1.f - wx) * (1.f - wy) * mx0 * my0;
    float W01 = wx * (1.f - wy) * mx1 * my0;
    float W10 = (1.f - wx) * wy * mx0 * my1;
    float W11 = wx * wy * mx1 * my1;
    int xc0 = min(max(x0, 0), W - 1), xc1 = min(max(x0 + 1, 0), W - 1);
    int yc0 = min(max(y0, 0), H - 1), yc1 = min(max(y0 + 1, 0), H - 1);
    int o00 = yc0 * W + xc0, o01 = yc0 * W + xc1;
    int o10 = yc1 * W + xc0, o11 = yc1 * W + xc1;

    float s = 0.f;
    for (int c = 0; c < nc_old; ++c) {
        const float* im = rd_old + (size_t)(b * 11 + c) * HW;
        float v = W00 * im[o00] + W01 * im[o01] + W10 * im[o10] + W11 * im[o11];
        rd_new[(size_t)(b * 11 + c) * HW + p] = v;
        if (c > 0) s += v;
    }
    rd_new[(size_t)(b * 11 + nc_old) * HW + p] = rn;
    s += rn;

    const float* phx = phi_old + (size_t)(b * 2 + 0) * HW;
    const float* phy = phi_old + (size_t)(b * 2 + 1) * HW;
    float pxn = W00 * phx[o00] + W01 * phx[o01] + W10 * phx[o10] + W11 * phx[o11];
    float pyn = W00 * phy[o00] + W01 * phy[o01] + W10 * phy[o10] + W11 * phy[o11];
    phi_new[(size_t)(b * 2 + 0) * HW + p] = pxn;
    phi_new[(size_t)(b * 2 + 1) * HW + p] = pyn;

    float mask = bilin(seg + (size_t)b * HW, pxn, pyn);
    float sw   = bilin(source + (size_t)b * HW, pxn, pyn);
    float img = sw + s * (MU * MU / (float)L) * mask;
    image_buf[idx] = img;
    image_out[idx] = img;
}

// ---------------------------------------------------------------- launch

extern "C" void kernel_launch(void* const* d_in, const int* in_sizes, int n_in,
                              void* d_out, int out_size, void* d_ws, size_t ws_size,
                              hipStream_t stream) {
    const float* source = (const float*)d_in[0];
    const float* seg    = (const float*)d_in[1];
    const float* z0     = (const float*)d_in[2];
    const float* w1     = (const float*)d_in[3];
    const float* b1     = (const float*)d_in[4];
    const float* w2     = (const float*)d_in[5];
    float* out = (float*)d_out;

    const size_t nPix = (size_t)B * HW;
    float* out_image  = out;
    float* out_fields = out + nPix;
    float* out_res    = out_fields + (size_t)L * nPix * 2;
    float* out_grads  = out_res + (size_t)(L + 1) * nPix;

    float* ws        = (float*)d_ws;
    float* image_buf = ws;                       // B*HW
    float* part_buf  = image_buf + nPix;         // 2*B*HW
    float* phi_buf0  = part_buf + 2 * nPix;      // 2*B*HW
    float* phi_buf1  = phi_buf0 + 2 * nPix;      // 2*B*HW
    float* rd_buf0   = phi_buf1 + 2 * nPix;      // 11*B*HW
    float* rd_buf1   = rd_buf0 + 11 * nPix;      // 11*B*HW
    float* phi_buf[2] = { phi_buf0, phi_buf1 };
    float* rd_buf[2]  = { rd_buf0, rd_buf1 };

    dim3 blk(256);
    int gPix = (int)((nPix + 255) / 256);

    init_kernel<<<gPix, blk, 0, stream>>>(source, z0, out_res, rd_buf[0], phi_buf[0], image_buf);

    int cur = 0;
    for (int i = 0; i < L; ++i) {
        dim3 gF(W / 32, H / 32, B);
        field_kernel<<<gF, 256, 0, stream>>>(image_buf, out_res + (size_t)i * nPix,
                                             out_grads + (size_t)i * 2 * nPix,
                                             out_fields + (size_t)i * 2 * nPix);
        dim3 gD(W / 16, H / 16, 2 * B);
        resblock_kernel<<<gD, 256, 0, stream>>>(out_res + (size_t)i * nPix, image_buf,
                                                w1 + (size_t)i * HID * 18,
                                                b1 + (size_t)i * HID,
                                                w2 + (size_t)i * HID * 9,
                                                part_buf);
        efg_kernel<<<gPix, blk, 0, stream>>>(out_fields + (size_t)i * 2 * nPix,
                                             out_res + (size_t)i * nPix,
                                             part_buf,
                                             out_res + (size_t)(i + 1) * nPix,
                                             rd_buf[cur], rd_buf[cur ^ 1], i + 1,
                                             phi_buf[cur], phi_buf[cur ^ 1],
                                             seg, source, image_buf, out_image);
        cur ^= 1;
    }
}

// Round 5
// 1154.798 us; speedup vs baseline: 2.8966x; 2.8966x over previous
//
#include <hip/hip_runtime.h>
#include <math.h>

#define L 10
#define B 4
#define H 256
#define W 256
#define HID 100
#define SIGMA 4.0f
#define KSIZE 25
#define KHALF 12
#define MU 0.02f
#define SLOPE 0.01f
#define HW (H*W)

// ---------------------------------------------------------------- helpers

__device__ __forceinline__ float tap2(const float* __restrict__ im, int y, int x) {
    return (x >= 0 && x < W && y >= 0 && y < H) ? im[y * W + x] : 0.f;
}

__device__ __forceinline__ float bilin(const float* __restrict__ im, float x, float y) {
    float xf = floorf(x), yf = floorf(y);
    int x0 = (int)xf, y0 = (int)yf;
    float wx = x - xf, wy = y - yf;
    float v00 = tap2(im, y0, x0),     v01 = tap2(im, y0, x0 + 1);
    float v10 = tap2(im, y0 + 1, x0), v11 = tap2(im, y0 + 1, x0 + 1);
    return v00 * (1.f - wx) * (1.f - wy) + v01 * wx * (1.f - wy)
         + v10 * (1.f - wx) * wy         + v11 * wx * wy;
}

__device__ __forceinline__ void gaussw(float g[KSIZE]) {
    float s = 0.f;
#pragma unroll
    for (int k = 0; k < KSIZE; ++k) {
        float r = ((float)k - (float)KHALF) * (1.f / SIGMA);
        float v = expf(-0.5f * r * r);
        g[k] = v; s += v;
    }
    float inv = 1.f / s;
#pragma unroll
    for (int k = 0; k < KSIZE; ++k) g[k] *= inv;
}

// ---------------------------------------------------------------- init

__global__ void init_kernel(const float* __restrict__ source, const float* __restrict__ z0,
                            float* __restrict__ res0_out, float* __restrict__ rd0,
                            float* __restrict__ phi0, float* __restrict__ image_buf) {
    int idx = blockIdx.x * 256 + threadIdx.x;
    if (idx >= B * HW) return;
    int b = idx / HW, p = idx % HW;
    int y = p / W, x = p % W;
    float z = z0[p];
    res0_out[idx] = z;
    rd0[(size_t)(b * 11 + 0) * HW + p] = z;
    image_buf[idx] = source[idx];
    phi0[(size_t)(b * 2 + 0) * HW + p] = (float)x;
    phi0[(size_t)(b * 2 + 1) * HW + p] = (float)y;
}

// ------------------------------------- fused sobel + t + vblur + hblur

__global__ __launch_bounds__(256)
void field_kernel(const float* __restrict__ img, const float* __restrict__ res,
                  float* __restrict__ grads_l, float* __restrict__ field_l) {
    __shared__ float s_img[58][59];
    __shared__ float s_t[2][56][57];
    __shared__ float s_vb[2][32][57];

    const int tid = threadIdx.x;
    const int b = blockIdx.z;
    const int TY0 = blockIdx.y * 32, TX0 = blockIdx.x * 32;
    const float* imb = img + (size_t)b * HW;
    const float* reb = res + (size_t)b * HW;

    for (int q = tid; q < 58 * 58; q += 256) {
        int sy = q / 58, sx = q % 58;
        int gy = min(max(TY0 - 13 + sy, 0), H - 1);
        int gx = min(max(TX0 - 13 + sx, 0), W - 1);
        s_img[sy][sx] = imb[gy * W + gx];
    }
    __syncthreads();

    for (int q = tid; q < 56 * 56; q += 256) {
        int py = q / 56, px = q % 56;
        int sy = py + 1, sx = px + 1;
        float a00 = s_img[sy-1][sx-1], a01 = s_img[sy-1][sx], a02 = s_img[sy-1][sx+1];
        float a10 = s_img[sy  ][sx-1],                         a12 = s_img[sy  ][sx+1];
        float a20 = s_img[sy+1][sx-1], a21 = s_img[sy+1][sx], a22 = s_img[sy+1][sx+1];
        float dx = (a02 - a00 + 2.f * (a12 - a10) + a22 - a20) * 0.125f;
        float dy = (a20 - a00 + 2.f * (a21 - a01) + a22 - a02) * 0.125f;
        int gy = TY0 - 12 + py, gx = TX0 - 12 + px;
        bool in = ((unsigned)gy < H) && ((unsigned)gx < W);
        float rv = in ? reb[gy * W + gx] : 0.f;
        s_t[0][py][px] = in ? -rv * dx : 0.f;
        s_t[1][py][px] = in ? -rv * dy : 0.f;
        if (py >= 12 && py < 44 && px >= 12 && px < 44) {
            grads_l[(size_t)(b * 2 + 0) * HW + gy * W + gx] = dx;
            grads_l[(size_t)(b * 2 + 1) * HW + gy * W + gx] = dy;
        }
    }
    __syncthreads();

    float g[KSIZE]; gaussw(g);

    for (int q = tid; q < 2 * 32 * 56; q += 256) {
        int ch = q / (32 * 56), r = q % (32 * 56);
        int vy = r / 56, vx = r % 56;
        float acc = 0.f;
#pragma unroll
        for (int k = 0; k < KSIZE; ++k) acc = fmaf(g[k], s_t[ch][vy + k][vx], acc);
        s_vb[ch][vy][vx] = acc;
    }
    __syncthreads();

    for (int q = tid; q < 2 * 32 * 32; q += 256) {
        int ch = q / 1024, p = q % 1024;
        int hy = p / 32, hx = p % 32;
        float acc = 0.f;
#pragma unroll
        for (int k = 0; k < KSIZE; ++k) acc = fmaf(g[k], s_vb[ch][hy][hx + k], acc);
        field_l[((size_t)(b * H + TY0 + hy) * W + TX0 + hx) * 2 + ch] = acc;
    }
}

// ------------------------------------------------- fused res_block v4
// 16x16 tile, channel-split (2 groups) across blockIdx.z -> 2048 blocks
// = 8 blocks/CU. __launch_bounds__(256,8) pins VGPR<=64 so all 8 fit;
// "#pragma unroll 1" on the chunk loop stops the compiler from fully
// unrolling and hoisting ~900 weight loads (R4: 256 VGPR -> scratch spill,
// 680 MB HBM traffic/dispatch).

#define NCH 10

__global__ __launch_bounds__(256, 8)
void resblock_kernel(const float* __restrict__ res_i, const float* __restrict__ img,
                     const float* __restrict__ w1, const float* __restrict__ b1,
                     const float* __restrict__ w2, float* __restrict__ part) {
    __shared__ float s_in[2][20][21];      // tile + halo2, zero-padded
    __shared__ float s_hid[NCH][18][20];   // hidden 18x18, stride 20 (even)

    const int tid = threadIdx.x;
    const int z = blockIdx.z;
    const int b = z & 3;
    const int g = z >> 2;                  // channel group 0/1 (50 ch each)
    const int TY0 = blockIdx.y * 16, TX0 = blockIdx.x * 16;

    for (int q = tid; q < 20 * 20; q += 256) {
        int ry = q / 20, rx = q % 20;
        int gy = TY0 - 2 + ry, gx = TX0 - 2 + rx;
        bool v = ((unsigned)gy < H) && ((unsigned)gx < W);
        size_t gp = (size_t)b * HW + gy * W + gx;
        s_in[0][ry][rx] = v ? res_i[gp] : 0.f;
        s_in[1][ry][rx] = v ? img[gp]   : 0.f;
    }
    __syncthreads();

    const int ty = tid >> 4, tx = tid & 15;
    float acc = 0.f;

#pragma unroll 1
    for (int cc = 0; cc < 5; ++cc) {
        // conv1: hidden 18x18 as 18 rows x 9 col-pairs = 162 units
        if (tid < 162) {
            int hy = tid / 9, hx2 = (tid % 9) * 2;
            int gy = TY0 - 1 + hy, gx0 = TX0 - 1 + hx2;
            float xv[2][3][4];
#pragma unroll
            for (int ic = 0; ic < 2; ++ic)
#pragma unroll
                for (int j = 0; j < 3; ++j)
#pragma unroll
                    for (int i = 0; i < 4; ++i)
                        xv[ic][j][i] = s_in[ic][hy + j][hx2 + i];
            bool gyok = ((unsigned)gy < H);
            bool in0 = gyok && ((unsigned)gx0 < W);
            bool in1 = gyok && ((unsigned)(gx0 + 1) < W);
#pragma unroll 2
            for (int c = 0; c < NCH; ++c) {
                int ch = g * 50 + cc * NCH + c;
                const float* wp = w1 + ch * 18;       // uniform -> s_load
                float bv = b1[ch];
                float h0 = bv, h1 = bv;
#pragma unroll
                for (int ic = 0; ic < 2; ++ic)
#pragma unroll
                    for (int j = 0; j < 3; ++j)
#pragma unroll
                        for (int i = 0; i < 3; ++i) {
                            float wv = wp[ic * 9 + j * 3 + i];
                            h0 = fmaf(wv, xv[ic][j][i],     h0);
                            h1 = fmaf(wv, xv[ic][j][i + 1], h1);
                        }
                h0 = (h0 >= 0.f) ? h0 : SLOPE * h0;
                h1 = (h1 >= 0.f) ? h1 : SLOPE * h1;
                // conv2 zero-pads the hidden map outside the image
                s_hid[c][hy][hx2]     = in0 ? h0 : 0.f;
                s_hid[c][hy][hx2 + 1] = in1 ? h1 : 0.f;
            }
        }
        __syncthreads();

#pragma unroll 1
        for (int c = 0; c < NCH; ++c) {
            const float* wq = w2 + (g * 50 + cc * NCH + c) * 9;  // uniform
#pragma unroll
            for (int j = 0; j < 3; ++j) {
                float v0 = s_hid[c][ty + j][tx + 0];
                float v1 = s_hid[c][ty + j][tx + 1];
                float v2 = s_hid[c][ty + j][tx + 2];
                acc = fmaf(wq[j * 3 + 0], v0, acc);
                acc = fmaf(wq[j * 3 + 1], v1, acc);
                acc = fmaf(wq[j * 3 + 2], v2, acc);
            }
        }
        __syncthreads();
    }

    size_t gp = (size_t)b * HW + (TY0 + ty) * W + TX0 + tx;
    part[(size_t)g * (B * HW) + gp] = acc;
}

// ------------------------------------------------- E+F+G fused warp/update
// also combines the two resblock partials into res_{i+1}

__global__ void efg_kernel(const float* __restrict__ field,
                           const float* __restrict__ res_prev,   // residuals[i]
                           const float* __restrict__ part,       // 2 x B*HW partials
                           float* __restrict__ res_next,         // residuals[i+1] out
                           const float* __restrict__ rd_old, float* __restrict__ rd_new,
                           int nc_old,
                           const float* __restrict__ phi_old, float* __restrict__ phi_new,
                           const float* __restrict__ seg, const float* __restrict__ source,
                           float* __restrict__ image_buf, float* __restrict__ image_out) {
    int idx = blockIdx.x * 256 + threadIdx.x;
    if (idx >= B * HW) return;
    int b = idx / HW, p = idx % HW;
    int y = p / W, x = p % W;

    float rn = res_prev[idx] + (part[idx] + part[(size_t)B * HW + idx]) * (1.f / (float)L);
    res_next[idx] = rn;

    float fx = field[((size_t)(b * HW + p)) * 2 + 0];
    float fy = field[((size_t)(b * HW + p)) * 2 + 1];
    float sx = (float)x - fx * (1.f / (float)L);
    float sy = (float)y - fy * (1.f / (float)L);

    float xf = floorf(sx), yf = floorf(sy);
    int x0 = (int)xf, y0 = (int)yf;
    float wx = sx - xf, wy = sy - yf;
    float mx0 = (x0 >= 0 && x0 < W) ? 1.f : 0.f;
    float mx1 = (x0 + 1 >= 0 && x0 + 1 < W) ? 1.f : 0.f;
    float my0 = (y0 >= 0 && y0 < H) ? 1.f : 0.f;
    float my1 = (y0 + 1 >= 0 && y0 + 1 < H) ? 1.f : 0.f;
    float W00 = (1.f - wx) * (1.f - wy) * mx0 * my0;
    float W01 = wx * (1.f - wy) * mx1 * my0;
    float W10 = (1.f - wx) * wy * mx0 * my1;
    float W11 = wx * wy * mx1 * my1;
    int xc0 = min(max(x0, 0), W - 1), xc1 = min(max(x0 + 1, 0), W - 1);
    int yc0 = min(max(y0, 0), H - 1), yc1 = min(max(y0 + 1, 0), H - 1);
    int o00 = yc0 * W + xc0, o01 = yc0 * W + xc1;
    int o10 = yc1 * W + xc0, o11 = yc1 * W + xc1;

    float s = 0.f;
    for (int c = 0; c < nc_old; ++c) {
        const float* im = rd_old + (size_t)(b * 11 + c) * HW;
        float v = W00 * im[o00] + W01 * im[o01] + W10 * im[o10] + W11 * im[o11];
        rd_new[(size_t)(b * 11 + c) * HW + p] = v;
        if (c > 0) s += v;
    }
    rd_new[(size_t)(b * 11 + nc_old) * HW + p] = rn;
    s += rn;

    const float* phx = phi_old + (size_t)(b * 2 + 0) * HW;
    const float* phy = phi_old + (size_t)(b * 2 + 1) * HW;
    float pxn = W00 * phx[o00] + W01 * phx[o01] + W10 * phx[o10] + W11 * phx[o11];
    float pyn = W00 * phy[o00] + W01 * phy[o01] + W10 * phy[o10] + W11 * phy[o11];
    phi_new[(size_t)(b * 2 + 0) * HW + p] = pxn;
    phi_new[(size_t)(b * 2 + 1) * HW + p] = pyn;

    float mask = bilin(seg + (size_t)b * HW, pxn, pyn);
    float sw   = bilin(source + (size_t)b * HW, pxn, pyn);
    float img = sw + s * (MU * MU / (float)L) * mask;
    image_buf[idx] = img;
    image_out[idx] = img;
}

// ---------------------------------------------------------------- launch

extern "C" void kernel_launch(void* const* d_in, const int* in_sizes, int n_in,
                              void* d_out, int out_size, void* d_ws, size_t ws_size,
                              hipStream_t stream) {
    const float* source = (const float*)d_in[0];
    const float* seg    = (const float*)d_in[1];
    const float* z0     = (const float*)d_in[2];
    const float* w1     = (const float*)d_in[3];
    const float* b1     = (const float*)d_in[4];
    const float* w2     = (const float*)d_in[5];
    float* out = (float*)d_out;

    const size_t nPix = (size_t)B * HW;
    float* out_image  = out;
    float* out_fields = out + nPix;
    float* out_res    = out_fields + (size_t)L * nPix * 2;
    float* out_grads  = out_res + (size_t)(L + 1) * nPix;

    float* ws        = (float*)d_ws;
    float* image_buf = ws;                       // B*HW
    float* part_buf  = image_buf + nPix;         // 2*B*HW
    float* phi_buf0  = part_buf + 2 * nPix;      // 2*B*HW
    float* phi_buf1  = phi_buf0 + 2 * nPix;      // 2*B*HW
    float* rd_buf0   = phi_buf1 + 2 * nPix;      // 11*B*HW
    float* rd_buf1   = rd_buf0 + 11 * nPix;      // 11*B*HW
    float* phi_buf[2] = { phi_buf0, phi_buf1 };
    float* rd_buf[2]  = { rd_buf0, rd_buf1 };

    dim3 blk(256);
    int gPix = (int)((nPix + 255) / 256);

    init_kernel<<<gPix, blk, 0, stream>>>(source, z0, out_res, rd_buf[0], phi_buf[0], image_buf);

    int cur = 0;
    for (int i = 0; i < L; ++i) {
        dim3 gF(W / 32, H / 32, B);
        field_kernel<<<gF, 256, 0, stream>>>(image_buf, out_res + (size_t)i * nPix,
                                             out_grads + (size_t)i * 2 * nPix,
                                             out_fields + (size_t)i * 2 * nPix);
        dim3 gD(W / 16, H / 16, 2 * B);
        resblock_kernel<<<gD, 256, 0, stream>>>(out_res + (size_t)i * nPix, image_buf,
                                                w1 + (size_t)i * HID * 18,
                                                b1 + (size_t)i * HID,
                                                w2 + (size_t)i * HID * 9,
                                                part_buf);
        efg_kernel<<<gPix, blk, 0, stream>>>(out_fields + (size_t)i * 2 * nPix,
                                             out_res + (size_t)i * nPix,
                                             part_buf,
                                             out_res + (size_t)(i + 1) * nPix,
                                             rd_buf[cur], rd_buf[cur ^ 1], i + 1,
                                             phi_buf[cur], phi_buf[cur ^ 1],
                                             seg, source, image_buf, out_image);
        cur ^= 1;
    }
}

// Round 6
// 737.496 us; speedup vs baseline: 4.5355x; 1.5658x over previous
//
#include <hip/hip_runtime.h>
#include <math.h>

#define L 10
#define B 4
#define H 256
#define W 256
#define HID 100
#define SIGMA 4.0f
#define KSIZE 25
#define KHALF 12
#define MU 0.02f
#define SLOPE 0.01f
#define HW (H*W)

// ---------------------------------------------------------------- helpers

__device__ __forceinline__ float tap2(const float* __restrict__ im, int y, int x) {
    return (x >= 0 && x < W && y >= 0 && y < H) ? im[y * W + x] : 0.f;
}

__device__ __forceinline__ float bilin(const float* __restrict__ im, float x, float y) {
    float xf = floorf(x), yf = floorf(y);
    int x0 = (int)xf, y0 = (int)yf;
    float wx = x - xf, wy = y - yf;
    float v00 = tap2(im, y0, x0),     v01 = tap2(im, y0, x0 + 1);
    float v10 = tap2(im, y0 + 1, x0), v11 = tap2(im, y0 + 1, x0 + 1);
    return v00 * (1.f - wx) * (1.f - wy) + v01 * wx * (1.f - wy)
         + v10 * (1.f - wx) * wy         + v11 * wx * wy;
}

__device__ __forceinline__ void gaussw(float g[KSIZE]) {
    float s = 0.f;
#pragma unroll
    for (int k = 0; k < KSIZE; ++k) {
        float r = ((float)k - (float)KHALF) * (1.f / SIGMA);
        float v = expf(-0.5f * r * r);
        g[k] = v; s += v;
    }
    float inv = 1.f / s;
#pragma unroll
    for (int k = 0; k < KSIZE; ++k) g[k] *= inv;
}

// ---------------------------------------------------------------- init

__global__ void init_kernel(const float* __restrict__ source, const float* __restrict__ z0,
                            float* __restrict__ res0_out, float* __restrict__ rd0,
                            float* __restrict__ phi0, float* __restrict__ image_buf) {
    int idx = blockIdx.x * 256 + threadIdx.x;
    if (idx >= B * HW) return;
    int b = idx / HW, p = idx % HW;
    int y = p / W, x = p % W;
    float z = z0[p];
    res0_out[idx] = z;
    rd0[(size_t)(b * 11 + 0) * HW + p] = z;
    image_buf[idx] = source[idx];
    phi0[(size_t)(b * 2 + 0) * HW + p] = (float)x;
    phi0[(size_t)(b * 2 + 1) * HW + p] = (float)y;
}

// ------------------------------------- fused sobel + t + vblur + hblur

__global__ __launch_bounds__(256)
void field_kernel(const float* __restrict__ img, const float* __restrict__ res,
                  float* __restrict__ grads_l, float* __restrict__ field_l) {
    __shared__ float s_img[58][59];
    __shared__ float s_t[2][56][57];
    __shared__ float s_vb[2][32][57];

    const int tid = threadIdx.x;
    const int b = blockIdx.z;
    const int TY0 = blockIdx.y * 32, TX0 = blockIdx.x * 32;
    const float* imb = img + (size_t)b * HW;
    const float* reb = res + (size_t)b * HW;

    for (int q = tid; q < 58 * 58; q += 256) {
        int sy = q / 58, sx = q % 58;
        int gy = min(max(TY0 - 13 + sy, 0), H - 1);
        int gx = min(max(TX0 - 13 + sx, 0), W - 1);
        s_img[sy][sx] = imb[gy * W + gx];
    }
    __syncthreads();

    for (int q = tid; q < 56 * 56; q += 256) {
        int py = q / 56, px = q % 56;
        int sy = py + 1, sx = px + 1;
        float a00 = s_img[sy-1][sx-1], a01 = s_img[sy-1][sx], a02 = s_img[sy-1][sx+1];
        float a10 = s_img[sy  ][sx-1],                         a12 = s_img[sy  ][sx+1];
        float a20 = s_img[sy+1][sx-1], a21 = s_img[sy+1][sx], a22 = s_img[sy+1][sx+1];
        float dx = (a02 - a00 + 2.f * (a12 - a10) + a22 - a20) * 0.125f;
        float dy = (a20 - a00 + 2.f * (a21 - a01) + a22 - a02) * 0.125f;
        int gy = TY0 - 12 + py, gx = TX0 - 12 + px;
        bool in = ((unsigned)gy < H) && ((unsigned)gx < W);
        float rv = in ? reb[gy * W + gx] : 0.f;
        s_t[0][py][px] = in ? -rv * dx : 0.f;
        s_t[1][py][px] = in ? -rv * dy : 0.f;
        if (py >= 12 && py < 44 && px >= 12 && px < 44) {
            grads_l[(size_t)(b * 2 + 0) * HW + gy * W + gx] = dx;
            grads_l[(size_t)(b * 2 + 1) * HW + gy * W + gx] = dy;
        }
    }
    __syncthreads();

    float g[KSIZE]; gaussw(g);

    for (int q = tid; q < 2 * 32 * 56; q += 256) {
        int ch = q / (32 * 56), r = q % (32 * 56);
        int vy = r / 56, vx = r % 56;
        float acc = 0.f;
#pragma unroll
        for (int k = 0; k < KSIZE; ++k) acc = fmaf(g[k], s_t[ch][vy + k][vx], acc);
        s_vb[ch][vy][vx] = acc;
    }
    __syncthreads();

    for (int q = tid; q < 2 * 32 * 32; q += 256) {
        int ch = q / 1024, p = q % 1024;
        int hy = p / 32, hx = p % 32;
        float acc = 0.f;
#pragma unroll
        for (int k = 0; k < KSIZE; ++k) acc = fmaf(g[k], s_vb[ch][hy][hx + k], acc);
        field_l[((size_t)(b * H + TY0 + hy) * W + TX0 + hx) * 2 + ch] = acc;
    }
}

// ------------------------------------------------- fused res_block v5
// 16x16 tile, channel-split (2 groups) across blockIdx.z -> 2048 blocks.
// __launch_bounds__(256,4): 128-VGPR budget -- R5's (256,8) capped at 64
// and the compiler spilled to scratch (292 MB HBM traffic/dispatch = the
// whole 108 us). 4 blocks/CU co-resident is enough latency hiding.

#define NCH 10

__global__ __launch_bounds__(256, 4)
void resblock_kernel(const float* __restrict__ res_i, const float* __restrict__ img,
                     const float* __restrict__ w1, const float* __restrict__ b1,
                     const float* __restrict__ w2, float* __restrict__ part) {
    __shared__ float s_in[2][20][21];      // tile + halo2, zero-padded
    __shared__ float s_hid[NCH][18][20];   // hidden 18x18, stride 20 (even)

    const int tid = threadIdx.x;
    const int z = blockIdx.z;
    const int b = z & 3;
    const int g = z >> 2;                  // channel group 0/1 (50 ch each)
    const int TY0 = blockIdx.y * 16, TX0 = blockIdx.x * 16;

    for (int q = tid; q < 20 * 20; q += 256) {
        int ry = q / 20, rx = q % 20;
        int gy = TY0 - 2 + ry, gx = TX0 - 2 + rx;
        bool v = ((unsigned)gy < H) && ((unsigned)gx < W);
        size_t gp = (size_t)b * HW + gy * W + gx;
        s_in[0][ry][rx] = v ? res_i[gp] : 0.f;
        s_in[1][ry][rx] = v ? img[gp]   : 0.f;
    }
    __syncthreads();

    const int ty = tid >> 4, tx = tid & 15;
    float acc = 0.f;

#pragma unroll 1
    for (int cc = 0; cc < 5; ++cc) {
        // conv1: hidden 18x18 as 18 rows x 9 col-pairs = 162 units
        if (tid < 162) {
            int hy = tid / 9, hx2 = (tid % 9) * 2;
            int gy = TY0 - 1 + hy, gx0 = TX0 - 1 + hx2;
            float xv[2][3][4];
#pragma unroll
            for (int ic = 0; ic < 2; ++ic)
#pragma unroll
                for (int j = 0; j < 3; ++j)
#pragma unroll
                    for (int i = 0; i < 4; ++i)
                        xv[ic][j][i] = s_in[ic][hy + j][hx2 + i];
            bool gyok = ((unsigned)gy < H);
            bool in0 = gyok && ((unsigned)gx0 < W);
            bool in1 = gyok && ((unsigned)(gx0 + 1) < W);
#pragma unroll 2
            for (int c = 0; c < NCH; ++c) {
                int ch = g * 50 + cc * NCH + c;
                const float* wp = w1 + ch * 18;       // uniform -> s_load
                float bv = b1[ch];
                float h0 = bv, h1 = bv;
#pragma unroll
                for (int ic = 0; ic < 2; ++ic)
#pragma unroll
                    for (int j = 0; j < 3; ++j)
#pragma unroll
                        for (int i = 0; i < 3; ++i) {
                            float wv = wp[ic * 9 + j * 3 + i];
                            h0 = fmaf(wv, xv[ic][j][i],     h0);
                            h1 = fmaf(wv, xv[ic][j][i + 1], h1);
                        }
                h0 = (h0 >= 0.f) ? h0 : SLOPE * h0;
                h1 = (h1 >= 0.f) ? h1 : SLOPE * h1;
                // conv2 zero-pads the hidden map outside the image
                s_hid[c][hy][hx2]     = in0 ? h0 : 0.f;
                s_hid[c][hy][hx2 + 1] = in1 ? h1 : 0.f;
            }
        }
        __syncthreads();

#pragma unroll 1
        for (int c = 0; c < NCH; ++c) {
            const float* wq = w2 + (g * 50 + cc * NCH + c) * 9;  // uniform
#pragma unroll
            for (int j = 0; j < 3; ++j) {
                float v0 = s_hid[c][ty + j][tx + 0];
                float v1 = s_hid[c][ty + j][tx + 1];
                float v2 = s_hid[c][ty + j][tx + 2];
                acc = fmaf(wq[j * 3 + 0], v0, acc);
                acc = fmaf(wq[j * 3 + 1], v1, acc);
                acc = fmaf(wq[j * 3 + 2], v2, acc);
            }
        }
        __syncthreads();
    }

    size_t gp = (size_t)b * HW + (TY0 + ty) * W + TX0 + tx;
    part[(size_t)g * (B * HW) + gp] = acc;
}

// ------------------------------------------------- E+F+G fused warp/update
// also combines the two resblock partials into res_{i+1}

__global__ void efg_kernel(const float* __restrict__ field,
                           const float* __restrict__ res_prev,   // residuals[i]
                           const float* __restrict__ part,       // 2 x B*HW partials
                           float* __restrict__ res_next,         // residuals[i+1] out
                           const float* __restrict__ rd_old, float* __restrict__ rd_new,
                           int nc_old,
                           const float* __restrict__ phi_old, float* __restrict__ phi_new,
                           const float* __restrict__ seg, const float* __restrict__ source,
                           float* __restrict__ image_buf, float* __restrict__ image_out) {
    int idx = blockIdx.x * 256 + threadIdx.x;
    if (idx >= B * HW) return;
    int b = idx / HW, p = idx % HW;
    int y = p / W, x = p % W;

    float rn = res_prev[idx] + (part[idx] + part[(size_t)B * HW + idx]) * (1.f / (float)L);
    res_next[idx] = rn;

    float fx = field[((size_t)(b * HW + p)) * 2 + 0];
    float fy = field[((size_t)(b * HW + p)) * 2 + 1];
    float sx = (float)x - fx * (1.f / (float)L);
    float sy = (float)y - fy * (1.f / (float)L);

    float xf = floorf(sx), yf = floorf(sy);
    int x0 = (int)xf, y0 = (int)yf;
    float wx = sx - xf, wy = sy - yf;
    float mx0 = (x0 >= 0 && x0 < W) ? 1.f : 0.f;
    float mx1 = (x0 + 1 >= 0 && x0 + 1 < W) ? 1.f : 0.f;
    float my0 = (y0 >= 0 && y0 < H) ? 1.f : 0.f;
    float my1 = (y0 + 1 >= 0 && y0 + 1 < H) ? 1.f : 0.f;
    float W00 = (1.f - wx) * (1.f - wy) * mx0 * my0;
    float W01 = wx * (1.f - wy) * mx1 * my0;
    float W10 = (1.f - wx) * wy * mx0 * my1;
    float W11 = wx * wy * mx1 * my1;
    int xc0 = min(max(x0, 0), W - 1), xc1 = min(max(x0 + 1, 0), W - 1);
    int yc0 = min(max(y0, 0), H - 1), yc1 = min(max(y0 + 1, 0), H - 1);
    int o00 = yc0 * W + xc0, o01 = yc0 * W + xc1;
    int o10 = yc1 * W + xc0, o11 = yc1 * W + xc1;

    float s = 0.f;
    for (int c = 0; c < nc_old; ++c) {
        const float* im = rd_old + (size_t)(b * 11 + c) * HW;
        float v = W00 * im[o00] + W01 * im[o01] + W10 * im[o10] + W11 * im[o11];
        rd_new[(size_t)(b * 11 + c) * HW + p] = v;
        if (c > 0) s += v;
    }
    rd_new[(size_t)(b * 11 + nc_old) * HW + p] = rn;
    s += rn;

    const float* phx = phi_old + (size_t)(b * 2 + 0) * HW;
    const float* phy = phi_old + (size_t)(b * 2 + 1) * HW;
    float pxn = W00 * phx[o00] + W01 * phx[o01] + W10 * phx[o10] + W11 * phx[o11];
    float pyn = W00 * phy[o00] + W01 * phy[o01] + W10 * phy[o10] + W11 * phy[o11];
    phi_new[(size_t)(b * 2 + 0) * HW + p] = pxn;
    phi_new[(size_t)(b * 2 + 1) * HW + p] = pyn;

    float mask = bilin(seg + (size_t)b * HW, pxn, pyn);
    float sw   = bilin(source + (size_t)b * HW, pxn, pyn);
    float img = sw + s * (MU * MU / (float)L) * mask;
    image_buf[idx] = img;
    image_out[idx] = img;
}

// ---------------------------------------------------------------- launch

extern "C" void kernel_launch(void* const* d_in, const int* in_sizes, int n_in,
                              void* d_out, int out_size, void* d_ws, size_t ws_size,
                              hipStream_t stream) {
    const float* source = (const float*)d_in[0];
    const float* seg    = (const float*)d_in[1];
    const float* z0     = (const float*)d_in[2];
    const float* w1     = (const float*)d_in[3];
    const float* b1     = (const float*)d_in[4];
    const float* w2     = (const float*)d_in[5];
    float* out = (float*)d_out;

    const size_t nPix = (size_t)B * HW;
    float* out_image  = out;
    float* out_fields = out + nPix;
    float* out_res    = out_fields + (size_t)L * nPix * 2;
    float* out_grads  = out_res + (size_t)(L + 1) * nPix;

    float* ws        = (float*)d_ws;
    float* image_buf = ws;                       // B*HW
    float* part_buf  = image_buf + nPix;         // 2*B*HW
    float* phi_buf0  = part_buf + 2 * nPix;      // 2*B*HW
    float* phi_buf1  = phi_buf0 + 2 * nPix;      // 2*B*HW
    float* rd_buf0   = phi_buf1 + 2 * nPix;      // 11*B*HW
    float* rd_buf1   = rd_buf0 + 11 * nPix;      // 11*B*HW
    float* phi_buf[2] = { phi_buf0, phi_buf1 };
    float* rd_buf[2]  = { rd_buf0, rd_buf1 };

    dim3 blk(256);
    int gPix = (int)((nPix + 255) / 256);

    init_kernel<<<gPix, blk, 0, stream>>>(source, z0, out_res, rd_buf[0], phi_buf[0], image_buf);

    int cur = 0;
    for (int i = 0; i < L; ++i) {
        dim3 gF(W / 32, H / 32, B);
        field_kernel<<<gF, 256, 0, stream>>>(image_buf, out_res + (size_t)i * nPix,
                                             out_grads + (size_t)i * 2 * nPix,
                                             out_fields + (size_t)i * 2 * nPix);
        dim3 gD(W / 16, H / 16, 2 * B);
        resblock_kernel<<<gD, 256, 0, stream>>>(out_res + (size_t)i * nPix, image_buf,
                                                w1 + (size_t)i * HID * 18,
                                                b1 + (size_t)i * HID,
                                                w2 + (size_t)i * HID * 9,
                                                part_buf);
        efg_kernel<<<gPix, blk, 0, stream>>>(out_fields + (size_t)i * 2 * nPix,
                                             out_res + (size_t)i * nPix,
                                             part_buf,
                                             out_res + (size_t)(i + 1) * nPix,
                                             rd_buf[cur], rd_buf[cur ^ 1], i + 1,
                                             phi_buf[cur], phi_buf[cur ^ 1],
                                             seg, source, image_buf, out_image);
        cur ^= 1;
    }
}

// Round 7
// 550.984 us; speedup vs baseline: 6.0709x; 1.3385x over previous
//
#include <hip/hip_runtime.h>
#include <math.h>

#define L 10
#define B 4
#define H 256
#define W 256
#define HID 100
#define SIGMA 4.0f
#define KSIZE 25
#define KHALF 12
#define MU 0.02f
#define SLOPE 0.01f
#define HW (H*W)

// ---------------------------------------------------------------- helpers

__device__ __forceinline__ float tap2(const float* __restrict__ im, int y, int x) {
    return (x >= 0 && x < W && y >= 0 && y < H) ? im[y * W + x] : 0.f;
}

__device__ __forceinline__ float bilin(const float* __restrict__ im, float x, float y) {
    float xf = floorf(x), yf = floorf(y);
    int x0 = (int)xf, y0 = (int)yf;
    float wx = x - xf, wy = y - yf;
    float v00 = tap2(im, y0, x0),     v01 = tap2(im, y0, x0 + 1);
    float v10 = tap2(im, y0 + 1, x0), v11 = tap2(im, y0 + 1, x0 + 1);
    return v00 * (1.f - wx) * (1.f - wy) + v01 * wx * (1.f - wy)
         + v10 * (1.f - wx) * wy         + v11 * wx * wy;
}

__device__ __forceinline__ void gaussw(float g[KSIZE]) {
    float s = 0.f;
#pragma unroll
    for (int k = 0; k < KSIZE; ++k) {
        float r = ((float)k - (float)KHALF) * (1.f / SIGMA);
        float v = expf(-0.5f * r * r);
        g[k] = v; s += v;
    }
    float inv = 1.f / s;
#pragma unroll
    for (int k = 0; k < KSIZE; ++k) g[k] *= inv;
}

// ---------------------------------------------------------------- init

__global__ void init_kernel(const float* __restrict__ source, const float* __restrict__ z0,
                            float* __restrict__ res0_out, float* __restrict__ rd0,
                            float* __restrict__ phi0, float* __restrict__ image_buf) {
    int idx = blockIdx.x * 256 + threadIdx.x;
    if (idx >= B * HW) return;
    int b = idx / HW, p = idx % HW;
    int y = p / W, x = p % W;
    float z = z0[p];
    res0_out[idx] = z;
    rd0[(size_t)(b * 11 + 0) * HW + p] = z;
    image_buf[idx] = source[idx];
    phi0[(size_t)(b * 2 + 0) * HW + p] = (float)x;
    phi0[(size_t)(b * 2 + 1) * HW + p] = (float)y;
}

// ------------------------------------- fused sobel + t + vblur + hblur

__global__ __launch_bounds__(256)
void field_kernel(const float* __restrict__ img, const float* __restrict__ res,
                  float* __restrict__ grads_l, float* __restrict__ field_l) {
    __shared__ float s_img[58][59];
    __shared__ float s_t[2][56][57];
    __shared__ float s_vb[2][32][57];

    const int tid = threadIdx.x;
    const int b = blockIdx.z;
    const int TY0 = blockIdx.y * 32, TX0 = blockIdx.x * 32;
    const float* imb = img + (size_t)b * HW;
    const float* reb = res + (size_t)b * HW;

    for (int q = tid; q < 58 * 58; q += 256) {
        int sy = q / 58, sx = q % 58;
        int gy = min(max(TY0 - 13 + sy, 0), H - 1);
        int gx = min(max(TX0 - 13 + sx, 0), W - 1);
        s_img[sy][sx] = imb[gy * W + gx];
    }
    __syncthreads();

    for (int q = tid; q < 56 * 56; q += 256) {
        int py = q / 56, px = q % 56;
        int sy = py + 1, sx = px + 1;
        float a00 = s_img[sy-1][sx-1], a01 = s_img[sy-1][sx], a02 = s_img[sy-1][sx+1];
        float a10 = s_img[sy  ][sx-1],                         a12 = s_img[sy  ][sx+1];
        float a20 = s_img[sy+1][sx-1], a21 = s_img[sy+1][sx], a22 = s_img[sy+1][sx+1];
        float dx = (a02 - a00 + 2.f * (a12 - a10) + a22 - a20) * 0.125f;
        float dy = (a20 - a00 + 2.f * (a21 - a01) + a22 - a02) * 0.125f;
        int gy = TY0 - 12 + py, gx = TX0 - 12 + px;
        bool in = ((unsigned)gy < H) && ((unsigned)gx < W);
        float rv = in ? reb[gy * W + gx] : 0.f;
        s_t[0][py][px] = in ? -rv * dx : 0.f;
        s_t[1][py][px] = in ? -rv * dy : 0.f;
        if (py >= 12 && py < 44 && px >= 12 && px < 44) {
            grads_l[(size_t)(b * 2 + 0) * HW + gy * W + gx] = dx;
            grads_l[(size_t)(b * 2 + 1) * HW + gy * W + gx] = dy;
        }
    }
    __syncthreads();

    float g[KSIZE]; gaussw(g);

    for (int q = tid; q < 2 * 32 * 56; q += 256) {
        int ch = q / (32 * 56), r = q % (32 * 56);
        int vy = r / 56, vx = r % 56;
        float acc = 0.f;
#pragma unroll
        for (int k = 0; k < KSIZE; ++k) acc = fmaf(g[k], s_t[ch][vy + k][vx], acc);
        s_vb[ch][vy][vx] = acc;
    }
    __syncthreads();

    for (int q = tid; q < 2 * 32 * 32; q += 256) {
        int ch = q / 1024, p = q % 1024;
        int hy = p / 32, hx = p % 32;
        float acc = 0.f;
#pragma unroll
        for (int k = 0; k < KSIZE; ++k) acc = fmaf(g[k], s_vb[ch][hy][hx + k], acc);
        field_l[((size_t)(b * H + TY0 + hy) * W + TX0 + hx) * 2 + ch] = acc;
    }
}

// ------------------------------------------------- fused res_block v6
// LDS-issue-bound fix (R6 analysis): channel-PAIR float2 hidden layout
// halves conv2 LDS instructions (45 b64 vs 90 b32 per px per chunk);
// conv1 writes one float4 (2 px x 2 ch) per k; conv1 input window xv[]
// hoisted out of the chunk loop (invariant). Same 16x16 tile, 2-group
// channel split, 2048 blocks. (256,4): 128-VGPR budget, no spill.

__global__ __launch_bounds__(256, 4)
void resblock_kernel(const float* __restrict__ res_i, const float* __restrict__ img,
                     const float* __restrict__ w1, const float* __restrict__ b1,
                     const float* __restrict__ w2, float* __restrict__ part) {
    __shared__ float s_in[2][20][21];        // tile + halo2, zero-padded
    __shared__ float2 s_hid[5][18][20];      // 5 channel-pairs, 18x18 (+pad)

    const int tid = threadIdx.x;
    const int z = blockIdx.z;
    const int b = z & 3;
    const int g = z >> 2;                    // channel group 0/1 (50 ch each)
    const int TY0 = blockIdx.y * 16, TX0 = blockIdx.x * 16;

    for (int q = tid; q < 20 * 20; q += 256) {
        int ry = q / 20, rx = q % 20;
        int gy = TY0 - 2 + ry, gx = TX0 - 2 + rx;
        bool v = ((unsigned)gy < H) && ((unsigned)gx < W);
        size_t gp = (size_t)b * HW + gy * W + gx;
        s_in[0][ry][rx] = v ? res_i[gp] : 0.f;
        s_in[1][ry][rx] = v ? img[gp]   : 0.f;
    }
    __syncthreads();

    // conv1 geometry (162 active threads; clamp for safe loads on the rest)
    const int qq  = (tid < 162) ? tid : 161;
    const int hy  = qq / 9, hx2 = (qq % 9) * 2;
    const int gy1 = TY0 - 1 + hy, gx0 = TX0 - 1 + hx2;
    const bool gyok = ((unsigned)gy1 < H);
    const bool in0 = gyok && ((unsigned)gx0 < W);
    const bool in1 = gyok && ((unsigned)(gx0 + 1) < W);

    // hoisted conv1 input window (chunk-invariant): 2ic x 3j x 4i
    float xv[2][3][4];
#pragma unroll
    for (int ic = 0; ic < 2; ++ic)
#pragma unroll
        for (int j = 0; j < 3; ++j)
#pragma unroll
            for (int i = 0; i < 4; ++i)
                xv[ic][j][i] = s_in[ic][hy + j][hx2 + i];

    const int ty = tid >> 4, tx = tid & 15;
    float acc = 0.f;

#pragma unroll 1
    for (int cc = 0; cc < 5; ++cc) {
        if (tid < 162) {
#pragma unroll 1
            for (int k = 0; k < 5; ++k) {
                int chA = g * 50 + cc * 10 + 2 * k;
                const float* wpA = w1 + chA * 18;        // uniform -> s_load
                const float* wpB = wpA + 18;
                float bA = b1[chA], bB = b1[chA + 1];
                float a0 = bA, a1 = bA, c0 = bB, c1 = bB;
#pragma unroll
                for (int ic = 0; ic < 2; ++ic)
#pragma unroll
                    for (int j = 0; j < 3; ++j)
#pragma unroll
                        for (int i = 0; i < 3; ++i) {
                            float wA = wpA[ic * 9 + j * 3 + i];
                            float wB = wpB[ic * 9 + j * 3 + i];
                            a0 = fmaf(wA, xv[ic][j][i],     a0);
                            a1 = fmaf(wA, xv[ic][j][i + 1], a1);
                            c0 = fmaf(wB, xv[ic][j][i],     c0);
                            c1 = fmaf(wB, xv[ic][j][i + 1], c1);
                        }
                a0 = (a0 >= 0.f) ? a0 : SLOPE * a0;
                a1 = (a1 >= 0.f) ? a1 : SLOPE * a1;
                c0 = (c0 >= 0.f) ? c0 : SLOPE * c0;
                c1 = (c1 >= 0.f) ? c1 : SLOPE * c1;
                // conv2 zero-pads hidden outside the image
                float4 wv;
                wv.x = in0 ? a0 : 0.f;  wv.y = in0 ? c0 : 0.f;   // px0 (chA,chB)
                wv.z = in1 ? a1 : 0.f;  wv.w = in1 ? c1 : 0.f;   // px1 (chA,chB)
                *(float4*)&s_hid[k][hy][hx2] = wv;               // 16B aligned
            }
        }
        __syncthreads();

#pragma unroll 1
        for (int k = 0; k < 5; ++k) {
            const float* wqA = w2 + (g * 50 + cc * 10 + 2 * k) * 9;  // uniform
            const float* wqB = wqA + 9;
#pragma unroll
            for (int j = 0; j < 3; ++j) {
                float2 v0 = s_hid[k][ty + j][tx + 0];
                float2 v1 = s_hid[k][ty + j][tx + 1];
                float2 v2 = s_hid[k][ty + j][tx + 2];
                acc = fmaf(wqA[j * 3 + 0], v0.x, acc);
                acc = fmaf(wqB[j * 3 + 0], v0.y, acc);
                acc = fmaf(wqA[j * 3 + 1], v1.x, acc);
                acc = fmaf(wqB[j * 3 + 1], v1.y, acc);
                acc = fmaf(wqA[j * 3 + 2], v2.x, acc);
                acc = fmaf(wqB[j * 3 + 2], v2.y, acc);
            }
        }
        __syncthreads();
    }

    size_t gp = (size_t)b * HW + (TY0 + ty) * W + TX0 + tx;
    part[(size_t)g * (B * HW) + gp] = acc;
}

// ------------------------------------------------- E+F+G fused warp/update
// also combines the two resblock partials into res_{i+1}

__global__ void efg_kernel(const float* __restrict__ field,
                           const float* __restrict__ res_prev,   // residuals[i]
                           const float* __restrict__ part,       // 2 x B*HW partials
                           float* __restrict__ res_next,         // residuals[i+1] out
                           const float* __restrict__ rd_old, float* __restrict__ rd_new,
                           int nc_old,
                           const float* __restrict__ phi_old, float* __restrict__ phi_new,
                           const float* __restrict__ seg, const float* __restrict__ source,
                           float* __restrict__ image_buf, float* __restrict__ image_out) {
    int idx = blockIdx.x * 256 + threadIdx.x;
    if (idx >= B * HW) return;
    int b = idx / HW, p = idx % HW;
    int y = p / W, x = p % W;

    float rn = res_prev[idx] + (part[idx] + part[(size_t)B * HW + idx]) * (1.f / (float)L);
    res_next[idx] = rn;

    float fx = field[((size_t)(b * HW + p)) * 2 + 0];
    float fy = field[((size_t)(b * HW + p)) * 2 + 1];
    float sx = (float)x - fx * (1.f / (float)L);
    float sy = (float)y - fy * (1.f / (float)L);

    float xf = floorf(sx), yf = floorf(sy);
    int x0 = (int)xf, y0 = (int)yf;
    float wx = sx - xf, wy = sy - yf;
    float mx0 = (x0 >= 0 && x0 < W) ? 1.f : 0.f;
    float mx1 = (x0 + 1 >= 0 && x0 + 1 < W) ? 1.f : 0.f;
    float my0 = (y0 >= 0 && y0 < H) ? 1.f : 0.f;
    float my1 = (y0 + 1 >= 0 && y0 + 1 < H) ? 1.f : 0.f;
    float W00 = (1.f - wx) * (1.f - wy) * mx0 * my0;
    float W01 = wx * (1.f - wy) * mx1 * my0;
    float W10 = (1.f - wx) * wy * mx0 * my1;
    float W11 = wx * wy * mx1 * my1;
    int xc0 = min(max(x0, 0), W - 1), xc1 = min(max(x0 + 1, 0), W - 1);
    int yc0 = min(max(y0, 0), H - 1), yc1 = min(max(y0 + 1, 0), H - 1);
    int o00 = yc0 * W + xc0, o01 = yc0 * W + xc1;
    int o10 = yc1 * W + xc0, o11 = yc1 * W + xc1;

    float s = 0.f;
    for (int c = 0; c < nc_old; ++c) {
        const float* im = rd_old + (size_t)(b * 11 + c) * HW;
        float v = W00 * im[o00] + W01 * im[o01] + W10 * im[o10] + W11 * im[o11];
        rd_new[(size_t)(b * 11 + c) * HW + p] = v;
        if (c > 0) s += v;
    }
    rd_new[(size_t)(b * 11 + nc_old) * HW + p] = rn;
    s += rn;

    const float* phx = phi_old + (size_t)(b * 2 + 0) * HW;
    const float* phy = phi_old + (size_t)(b * 2 + 1) * HW;
    float pxn = W00 * phx[o00] + W01 * phx[o01] + W10 * phx[o10] + W11 * phx[o11];
    float pyn = W00 * phy[o00] + W01 * phy[o01] + W10 * phy[o10] + W11 * phy[o11];
    phi_new[(size_t)(b * 2 + 0) * HW + p] = pxn;
    phi_new[(size_t)(b * 2 + 1) * HW + p] = pyn;

    float mask = bilin(seg + (size_t)b * HW, pxn, pyn);
    float sw   = bilin(source + (size_t)b * HW, pxn, pyn);
    float img = sw + s * (MU * MU / (float)L) * mask;
    image_buf[idx] = img;
    image_out[idx] = img;
}

// ---------------------------------------------------------------- launch

extern "C" void kernel_launch(void* const* d_in, const int* in_sizes, int n_in,
                              void* d_out, int out_size, void* d_ws, size_t ws_size,
                              hipStream_t stream) {
    const float* source = (const float*)d_in[0];
    const float* seg    = (const float*)d_in[1];
    const float* z0     = (const float*)d_in[2];
    const float* w1     = (const float*)d_in[3];
    const float* b1     = (const float*)d_in[4];
    const float* w2     = (const float*)d_in[5];
    float* out = (float*)d_out;

    const size_t nPix = (size_t)B * HW;
    float* out_image  = out;
    float* out_fields = out + nPix;
    float* out_res    = out_fields + (size_t)L * nPix * 2;
    float* out_grads  = out_res + (size_t)(L + 1) * nPix;

    float* ws        = (float*)d_ws;
    float* image_buf = ws;                       // B*HW
    float* part_buf  = image_buf + nPix;         // 2*B*HW
    float* phi_buf0  = part_buf + 2 * nPix;      // 2*B*HW
    float* phi_buf1  = phi_buf0 + 2 * nPix;      // 2*B*HW
    float* rd_buf0   = phi_buf1 + 2 * nPix;      // 11*B*HW
    float* rd_buf1   = rd_buf0 + 11 * nPix;      // 11*B*HW
    float* phi_buf[2] = { phi_buf0, phi_buf1 };
    float* rd_buf[2]  = { rd_buf0, rd_buf1 };

    dim3 blk(256);
    int gPix = (int)((nPix + 255) / 256);

    init_kernel<<<gPix, blk, 0, stream>>>(source, z0, out_res, rd_buf[0], phi_buf[0], image_buf);

    int cur = 0;
    for (int i = 0; i < L; ++i) {
        dim3 gF(W / 32, H / 32, B);
        field_kernel<<<gF, 256, 0, stream>>>(image_buf, out_res + (size_t)i * nPix,
                                             out_grads + (size_t)i * 2 * nPix,
                                             out_fields + (size_t)i * 2 * nPix);
        dim3 gD(W / 16, H / 16, 2 * B);
        resblock_kernel<<<gD, 256, 0, stream>>>(out_res + (size_t)i * nPix, image_buf,
                                                w1 + (size_t)i * HID * 18,
                                                b1 + (size_t)i * HID,
                                                w2 + (size_t)i * HID * 9,
                                                part_buf);
        efg_kernel<<<gPix, blk, 0, stream>>>(out_fields + (size_t)i * 2 * nPix,
                                             out_res + (size_t)i * nPix,
                                             part_buf,
                                             out_res + (size_t)(i + 1) * nPix,
                                             rd_buf[cur], rd_buf[cur ^ 1], i + 1,
                                             phi_buf[cur], phi_buf[cur ^ 1],
                                             seg, source, image_buf, out_image);
        cur ^= 1;
    }
}